// Round 14
// baseline (202.333 us; speedup 1.0000x reference)
//
#include <hip/hip_runtime.h>
#include <hip/hip_bf16.h>
#include <stdint.h>

#define M_DIM 8192
#define IN_F  4096
#define OUT_F 4096
#define NFP   256
#define NTI8  32              // i8 byte-tiles (4096 B / 128 B)
#define NTB   4               // bf16 tail byte-tiles (512 B / 128 B)

typedef __attribute__((ext_vector_type(4)))  int   v4i;
typedef __attribute__((ext_vector_type(8)))  short short8;
typedef __attribute__((ext_vector_type(4)))  float f32x4;

__device__ __forceinline__ void stage16(const void* g, void* l) {
    __builtin_amdgcn_global_load_lds(
        (const __attribute__((address_space(1))) int*)g,
        (__attribute__((address_space(3))) int*)l,
        16, 0, 0);
}

#define SB() __builtin_amdgcn_sched_barrier(0)
#define BARRIER() do { SB(); __builtin_amdgcn_s_barrier(); SB(); } while (0)

// ---------------------------------------------------------------------------
// Kernel 1: per-row quantization, 4 rows per block (verified R12/R13).
// ---------------------------------------------------------------------------
__global__ __launch_bounds__(256)
void quant_rows(const float* __restrict__ x,
                const int* __restrict__ ind,
                char* __restrict__ qx,
                __hip_bfloat16* __restrict__ acts,
                float* __restrict__ xscale)
{
    __shared__ short omap[IN_F];
    __shared__ float red[4];
    __shared__ float s_xs;

    const int t = threadIdx.x;

    #pragma unroll
    for (int i = 0; i < IN_F / 256; ++i) omap[t + i * 256] = -1;
    __syncthreads();
    omap[ind[t]] = (short)t;
    __syncthreads();

    short om[16];
    #pragma unroll
    for (int j = 0; j < 16; ++j) om[j] = omap[t * 16 + j];

    for (int r = 0; r < 4; ++r) {
        const int row = blockIdx.x * 4 + r;

        const float* xr = x + (size_t)row * IN_F + t * 16;
        float v[16];
        #pragma unroll
        for (int j = 0; j < 4; ++j) {
            float4 f = *(const float4*)(xr + j * 4);
            v[j*4+0] = f.x; v[j*4+1] = f.y; v[j*4+2] = f.z; v[j*4+3] = f.w;
        }

        float m_nz = 0.f;
        #pragma unroll
        for (int j = 0; j < 16; ++j) {
            float a = fabsf(v[j]);
            if (om[j] < 0) m_nz = fmaxf(m_nz, a);
        }
        #pragma unroll
        for (int off = 32; off > 0; off >>= 1)
            m_nz = fmaxf(m_nz, __shfl_down(m_nz, off));
        if ((t & 63) == 0) red[t >> 6] = m_nz;
        __syncthreads();
        if (t == 0) {
            float a = fmaxf(fmaxf(red[0], red[1]), fmaxf(red[2], red[3]));
            xscale[row] = a / 127.0f;
            s_xs = (a > 0.f) ? (a / 127.0f) : 1.0f;
        }
        __syncthreads();
        const float xs = s_xs;

        union { char c[16]; int4 q; } u;
        #pragma unroll
        for (int j = 0; j < 16; ++j) {
            if (om[j] >= 0) {
                acts[(size_t)row * NFP + om[j]] = __float2bfloat16(v[j] / xs);
                u.c[j] = 0;
            } else {
                float rr = rintf(v[j] / xs);          // half-to-even == jnp.round
                rr = fminf(fmaxf(rr, -128.f), 127.f);
                u.c[j] = (char)(int)rr;
            }
        }
        *(int4*)(qx + (size_t)row * IN_F + t * 16) = u.q;
    }
}

// ---------------------------------------------------------------------------
// Kernel 2: weight int32 -> int8 (exact) + outlier gather (verified).
// ---------------------------------------------------------------------------
__global__ __launch_bounds__(256)
void conv_w(const int* __restrict__ qw, const int* __restrict__ ind,
            char* __restrict__ qb, __hip_bfloat16* __restrict__ wob)
{
    const int n = blockIdx.x;
    const int t = threadIdx.x;
    const int* src = qw + (size_t)n * IN_F + t * 16;
    union { char c[16]; int4 q; } u;
    #pragma unroll
    for (int j = 0; j < 4; ++j) {
        int4 raw = *(const int4*)(src + j * 4);
        u.c[j*4+0] = (char)raw.x; u.c[j*4+1] = (char)raw.y;
        u.c[j*4+2] = (char)raw.z; u.c[j*4+3] = (char)raw.w;
    }
    *(int4*)(qb + (size_t)n * IN_F + t * 16) = u.q;
    wob[(size_t)n * NFP + t] = __float2bfloat16((float)qw[(size_t)n * IN_F + ind[t]]);
}

// ---------------------------------------------------------------------------
// Kernel 3: R13 structure (147us, 46.5% MfmaUtil) with ONE change:
// WAVE-DEPENDENT K-ORDER. Odd waves (wv&1) process the k1 slice first.
// Mechanism (T5 prerequisite): barrier-lockstep made all 8 waves read LDS
// simultaneously then MFMA simultaneously -> port and matrix pipe alternate
// idle. With half the waves offset by one k-slice, one wave of each SIMD
// pair is MFMAing while the other reads -> port hides under pipe.
// Hazard audit unchanged: both orders consume all B-reads of buf c before
// the mid-tile barrier; region 2 reads A only; integer acc order-free.
// ---------------------------------------------------------------------------
#define LOADA8(MB, KK) \
    { _Pragma("unroll") for (int i = 0; i < 4; ++i) \
        af[i] = *(const v4i*)&Abuf[(((MB)+i)*16 + fr)*128 + ((((KK)*64) + kq4*16) ^ rsw)]; }
#define LOADB8(KK) \
    { _Pragma("unroll") for (int n = 0; n < 4; ++n) \
        bf4[n] = *(const v4i*)&Bbuf[(wn1*64 + n*16 + fr)*128 + ((((KK)*64) + kq4*16) ^ rsw)]; }
#define MFMA_I8(MB) \
    { _Pragma("unroll") for (int i = 0; i < 4; ++i) \
      _Pragma("unroll") for (int n = 0; n < 4; ++n) \
        acci[(MB)+i][n] = __builtin_amdgcn_mfma_i32_16x16x64_i8(af[i], bf4[n], acci[(MB)+i][n], 0, 0, 0); }

#define LOADAB(MB, KK) \
    { _Pragma("unroll") for (int i = 0; i < 4; ++i) \
        ab[i] = *(const short8*)&Abuf[(((MB)+i)*16 + fr)*128 + ((((KK)*64) + kq4*16) ^ rsw)]; }
#define LOADBB(KK) \
    { _Pragma("unroll") for (int n = 0; n < 4; ++n) \
        bb[n] = *(const short8*)&Bbuf[(wn1*64 + n*16 + fr)*128 + ((((KK)*64) + kq4*16) ^ rsw)]; }
#define MFMA_BF(MB) \
    { _Pragma("unroll") for (int i = 0; i < 4; ++i) \
      _Pragma("unroll") for (int n = 0; n < 4; ++n) \
        accf[(MB)+i][n] = __builtin_amdgcn_mfma_f32_16x16x32_bf16(ab[i], bb[n], accf[(MB)+i][n], 0, 0, 0); }

__global__ __launch_bounds__(512, 2)
void gemm_mix(const char* __restrict__ Aq,  // qx   M x 4096 i8
              const char* __restrict__ Bq,  // qb   N x 4096 i8
              const char* __restrict__ Ab,  // acts M x 512B bf16
              const char* __restrict__ Bb,  // wob  N x 512B bf16
              const float* __restrict__ rscale,
              const float* __restrict__ cscale,
              const float* __restrict__ bias,
              float* __restrict__ out)
{
    __shared__ __attribute__((aligned(16))) char smem[131072];   // 128 KiB

    const int tid = threadIdx.x;
    const int wv = tid >> 6, lane = tid & 63;
    const int wm = wv >> 2, wn = wv & 3;
    const int wn1 = wn & 1, whb = wn >> 1;
    const int fr = lane & 15, kq4 = lane >> 4;
    const int rsw = (fr & 7) << 4;               // read-side XOR (bytes)
    const int ko  = wv & 1;                      // per-wave k-slice order

    // 2D XCD map: xcd = bid&7 owns an 8bm x 8bn square (bijective, 512 blocks)
    const int bid = blockIdx.x;
    const int xcd = bid & 7, loc = bid >> 3;     // loc in 0..63
    const int bm = ((xcd & 3) * 8 + (loc & 7)) * 256;    // 0..31 tiles
    const int bn = ((xcd >> 2) * 8 + (loc >> 3)) * 256;  // 0..15 tiles

    const int srow = tid >> 3;                   // 0..63
    const int scb  = ((tid & 7) * 16) ^ ((srow & 7) << 4);   // pre-swizzled col

    auto stageA8 = [&](int T, int h, int c) {
        const char* src = Aq + (size_t)(bm + h * 128 + srow) * IN_F + T * 128 + scb;
        char* dst = smem + c * 65536 + h * 16384 + wv * 1024;
        stage16(src, dst);
        stage16(src + (size_t)64 * IN_F, dst + 8192);
    };
    auto stageB8 = [&](int T, int h, int c) {
        const char* src = Bq + (size_t)(bn + h * 128 + srow) * IN_F + T * 128 + scb;
        char* dst = smem + c * 65536 + 32768 + h * 16384 + wv * 1024;
        stage16(src, dst);
        stage16(src + (size_t)64 * IN_F, dst + 8192);
    };
    auto stageAb = [&](int T, int h, int c) {
        const char* src = Ab + (size_t)(bm + h * 128 + srow) * 512 + T * 128 + scb;
        char* dst = smem + c * 65536 + h * 16384 + wv * 1024;
        stage16(src, dst);
        stage16(src + (size_t)64 * 512, dst + 8192);
    };
    auto stageBb = [&](int T, int h, int c) {
        const char* src = Bb + (size_t)(bn + h * 128 + srow) * 512 + T * 128 + scb;
        char* dst = smem + c * 65536 + 32768 + h * 16384 + wv * 1024;
        stage16(src, dst);
        stage16(src + (size_t)64 * 512, dst + 8192);
    };

    // =========================== Loop 1: int8 ===========================
    v4i acci[8][4] = {};
    {
        v4i af[4], bf4[4];

        stageB8(0, 0, 0); stageB8(0, 1, 0);
        stageA8(0, 0, 0); stageA8(0, 1, 0);
        stageB8(1, 0, 1); stageB8(1, 1, 1);
        SB();
        asm volatile("s_waitcnt vmcnt(4)" ::: "memory");
        BARRIER();

        for (int t = 0; t < NTI8; ++t) {
            const int c = t & 1;
            const char* Abuf = smem + c * 65536 + wm * 16384;
            const char* Bbuf = smem + c * 65536 + 32768 + whb * 16384;

            // ---- region 1: stages + 3 clusters; even waves k-order {ko,
            // ko, ko^1}, odd waves the mirror -> port/pipe interleave ----
            if (t + 1 < NTI8) { stageA8(t + 1, 0, c ^ 1); stageA8(t + 1, 1, c ^ 1); }
            LOADB8(ko);
            LOADA8(0, ko);
            __builtin_amdgcn_s_setprio(1);
            MFMA_I8(0);
            __builtin_amdgcn_s_setprio(0);
            LOADA8(4, ko);
            __builtin_amdgcn_s_setprio(1);
            MFMA_I8(4);
            __builtin_amdgcn_s_setprio(0);
            LOADB8(ko ^ 1);
            LOADA8(0, ko ^ 1);
            __builtin_amdgcn_s_setprio(1);
            MFMA_I8(0);
            __builtin_amdgcn_s_setprio(0);
            BARRIER();   // all waves consumed both B k-slices of buf c
            // ---- region 2: stage B(t+2) into freed B-region + last cluster ----
            LOADA8(4, ko ^ 1);
            if (t + 2 < NTI8) { stageB8(t + 2, 0, c); stageB8(t + 2, 1, c); }
            __builtin_amdgcn_s_setprio(1);
            MFMA_I8(4);
            __builtin_amdgcn_s_setprio(0);
            SB();
            if (t < NTI8 - 2)       asm volatile("s_waitcnt vmcnt(4)" ::: "memory");
            else if (t == NTI8 - 2) asm volatile("s_waitcnt vmcnt(0)" ::: "memory");
            BARRIER();   // end of tile: t+1 buffers ready
        }
    }

    // exact i32 -> f32 convert, per fragment
    f32x4 accf[8][4];
    #pragma unroll
    for (int m = 0; m < 8; ++m)
        #pragma unroll
        for (int n = 0; n < 4; ++n) {
            const v4i q = acci[m][n];
            f32x4 f;
            #pragma unroll
            for (int r = 0; r < 4; ++r) f[r] = (float)q[r];
            accf[m][n] = f;
        }

    // ========================== Loop 2: bf16 tail ==========================
    {
        short8 ab[4], bb[4];

        stageBb(0, 0, 0); stageBb(0, 1, 0);
        stageAb(0, 0, 0); stageAb(0, 1, 0);
        stageBb(1, 0, 1); stageBb(1, 1, 1);
        SB();
        asm volatile("s_waitcnt vmcnt(4)" ::: "memory");
        BARRIER();

        for (int t = 0; t < NTB; ++t) {
            const int c = t & 1;
            const char* Abuf = smem + c * 65536 + wm * 16384;
            const char* Bbuf = smem + c * 65536 + 32768 + whb * 16384;

            if (t + 1 < NTB) { stageAb(t + 1, 0, c ^ 1); stageAb(t + 1, 1, c ^ 1); }
            LOADBB(ko);
            LOADAB(0, ko);
            __builtin_amdgcn_s_setprio(1);
            MFMA_BF(0);
            __builtin_amdgcn_s_setprio(0);
            LOADAB(4, ko);
            __builtin_amdgcn_s_setprio(1);
            MFMA_BF(4);
            __builtin_amdgcn_s_setprio(0);
            LOADBB(ko ^ 1);
            LOADAB(0, ko ^ 1);
            __builtin_amdgcn_s_setprio(1);
            MFMA_BF(0);
            __builtin_amdgcn_s_setprio(0);
            BARRIER();
            LOADAB(4, ko ^ 1);
            if (t + 2 < NTB) { stageBb(t + 2, 0, c); stageBb(t + 2, 1, c); }
            __builtin_amdgcn_s_setprio(1);
            MFMA_BF(4);
            __builtin_amdgcn_s_setprio(0);
            SB();
            if (t < NTB - 2)       asm volatile("s_waitcnt vmcnt(4)" ::: "memory");
            else if (t == NTB - 2) asm volatile("s_waitcnt vmcnt(0)" ::: "memory");
            BARRIER();
        }
    }

    // epilogue: 16x16 C/D layout col = lane&15, row = (lane>>4)*4 + reg [m89]
    #pragma unroll
    for (int m = 0; m < 8; ++m) {
        const int rbase = bm + wm * 128 + m * 16 + kq4 * 4;
        #pragma unroll
        for (int n = 0; n < 4; ++n) {
            const int col = bn + wn * 64 + n * 16 + fr;
            const float csv = cscale[col];
            const float badd = bias[col];
            #pragma unroll
            for (int r = 0; r < 4; ++r) {
                const int row = rbase + r;
                out[(size_t)row * OUT_F + col] =
                    accf[m][n][r] * rscale[row] * csv + badd;
            }
        }
    }
}

// ---------------------------------------------------------------------------
extern "C" void kernel_launch(void* const* d_in, const int* in_sizes, int n_in,
                              void* d_out, int out_size, void* d_ws, size_t ws_size,
                              hipStream_t stream)
{
    const float* x         = (const float*)d_in[0];
    const int*   q_weight  = (const int*)d_in[1];    // int32 on device
    const float* scale_col = (const float*)d_in[2];
    const float* bias      = (const float*)d_in[3];
    const int*   ind       = (const int*)d_in[4];
    float*       out       = (float*)d_out;

    // workspace (~54 MB)
    char*           qx   = (char*)d_ws;                              // M x IN_F i8
    char*           qb   = qx + (size_t)M_DIM * IN_F;                // OUT_F x IN_F i8
    __hip_bfloat16* acts = (__hip_bfloat16*)(qb + (size_t)OUT_F * IN_F);  // M x NFP
    __hip_bfloat16* wob  = acts + (size_t)M_DIM * NFP;               // OUT_F x NFP
    float*          xs   = (float*)(wob + (size_t)OUT_F * NFP);      // M

    const size_t need = (size_t)((char*)(xs + M_DIM) - (char*)d_ws);
    if (ws_size < need) return;

    quant_rows<<<dim3(M_DIM / 4), dim3(256), 0, stream>>>(x, ind, qx, acts, xs);
    conv_w<<<dim3(OUT_F), dim3(256), 0, stream>>>(q_weight, ind, qb, wob);

    gemm_mix<<<dim3((M_DIM / 256) * (OUT_F / 256)), dim3(512), 0, stream>>>(
        qx, qb, (const char*)acts, (const char*)wob,
        xs, scale_col, bias, out);
}

// Round 16
// 199.315 us; speedup vs baseline: 1.0151x; 1.0151x over previous
//
#include <hip/hip_runtime.h>
#include <hip/hip_bf16.h>
#include <stdint.h>

#define M_DIM 8192
#define IN_F  4096
#define OUT_F 4096
#define NFP   256
#define NTI8  32              // i8 byte-tiles (4096 B / 128 B)
#define NTB   4               // bf16 tail byte-tiles (512 B / 128 B)

typedef __attribute__((ext_vector_type(4)))  int   v4i;
typedef __attribute__((ext_vector_type(8)))  short short8;
typedef __attribute__((ext_vector_type(4)))  float f32x4;

__device__ __forceinline__ void stage16(const void* g, void* l) {
    __builtin_amdgcn_global_load_lds(
        (const __attribute__((address_space(1))) int*)g,
        (__attribute__((address_space(3))) int*)l,
        16, 0, 0);
}

#define SB() __builtin_amdgcn_sched_barrier(0)
#define BARRIER() do { SB(); __builtin_amdgcn_s_barrier(); SB(); } while (0)

// ---------------------------------------------------------------------------
// Kernel 1: per-row quantization, 4 rows per block (verified R12-R14).
// ---------------------------------------------------------------------------
__global__ __launch_bounds__(256)
void quant_rows(const float* __restrict__ x,
                const int* __restrict__ ind,
                char* __restrict__ qx,
                __hip_bfloat16* __restrict__ acts,
                float* __restrict__ xscale)
{
    __shared__ short omap[IN_F];
    __shared__ float red[4];
    __shared__ float s_xs;

    const int t = threadIdx.x;

    #pragma unroll
    for (int i = 0; i < IN_F / 256; ++i) omap[t + i * 256] = -1;
    __syncthreads();
    omap[ind[t]] = (short)t;
    __syncthreads();

    short om[16];
    #pragma unroll
    for (int j = 0; j < 16; ++j) om[j] = omap[t * 16 + j];

    for (int r = 0; r < 4; ++r) {
        const int row = blockIdx.x * 4 + r;

        const float* xr = x + (size_t)row * IN_F + t * 16;
        float v[16];
        #pragma unroll
        for (int j = 0; j < 4; ++j) {
            float4 f = *(const float4*)(xr + j * 4);
            v[j*4+0] = f.x; v[j*4+1] = f.y; v[j*4+2] = f.z; v[j*4+3] = f.w;
        }

        float m_nz = 0.f;
        #pragma unroll
        for (int j = 0; j < 16; ++j) {
            float a = fabsf(v[j]);
            if (om[j] < 0) m_nz = fmaxf(m_nz, a);
        }
        #pragma unroll
        for (int off = 32; off > 0; off >>= 1)
            m_nz = fmaxf(m_nz, __shfl_down(m_nz, off));
        if ((t & 63) == 0) red[t >> 6] = m_nz;
        __syncthreads();
        if (t == 0) {
            float a = fmaxf(fmaxf(red[0], red[1]), fmaxf(red[2], red[3]));
            xscale[row] = a / 127.0f;
            s_xs = (a > 0.f) ? (a / 127.0f) : 1.0f;
        }
        __syncthreads();
        const float xs = s_xs;

        union { char c[16]; int4 q; } u;
        #pragma unroll
        for (int j = 0; j < 16; ++j) {
            if (om[j] >= 0) {
                acts[(size_t)row * NFP + om[j]] = __float2bfloat16(v[j] / xs);
                u.c[j] = 0;
            } else {
                float rr = rintf(v[j] / xs);          // half-to-even == jnp.round
                rr = fminf(fmaxf(rr, -128.f), 127.f);
                u.c[j] = (char)(int)rr;
            }
        }
        *(int4*)(qx + (size_t)row * IN_F + t * 16) = u.q;
    }
}

// ---------------------------------------------------------------------------
// Kernel 2: weight int32 -> int8 (exact) + outlier gather (verified).
// ---------------------------------------------------------------------------
__global__ __launch_bounds__(256)
void conv_w(const int* __restrict__ qw, const int* __restrict__ ind,
            char* __restrict__ qb, __hip_bfloat16* __restrict__ wob)
{
    const int n = blockIdx.x;
    const int t = threadIdx.x;
    const int* src = qw + (size_t)n * IN_F + t * 16;
    union { char c[16]; int4 q; } u;
    #pragma unroll
    for (int j = 0; j < 4; ++j) {
        int4 raw = *(const int4*)(src + j * 4);
        u.c[j*4+0] = (char)raw.x; u.c[j*4+1] = (char)raw.y;
        u.c[j*4+2] = (char)raw.z; u.c[j*4+3] = (char)raw.w;
    }
    *(int4*)(qb + (size_t)n * IN_F + t * 16) = u.q;
    wob[(size_t)n * NFP + t] = __float2bfloat16((float)qw[(size_t)n * IN_F + ind[t]]);
}

// ---------------------------------------------------------------------------
// Kernel 3: R13 schedule + induction-variable addressing (R15), with the
// R15 bug fixed: bf16 tail tile t=1 MUST stage B(3)->buf1 (R13 staged
// B(t+2) for t<2; the unrolled call had doB=false -> tile 3 read stale B(1)).
// ---------------------------------------------------------------------------
#define LDA8(P, MB) \
    { _Pragma("unroll") for (int i = 0; i < 4; ++i) \
        af[i] = *(const v4i*)((P) + ((MB)+i)*2048); }
#define LDB8(P) \
    { _Pragma("unroll") for (int n = 0; n < 4; ++n) \
        bf4[n] = *(const v4i*)((P) + n*2048); }
#define MFMA_I8(MB) \
    { _Pragma("unroll") for (int i = 0; i < 4; ++i) \
      _Pragma("unroll") for (int n = 0; n < 4; ++n) \
        acci[(MB)+i][n] = __builtin_amdgcn_mfma_i32_16x16x64_i8(af[i], bf4[n], acci[(MB)+i][n], 0, 0, 0); }

#define LDAB(P, MB) \
    { _Pragma("unroll") for (int i = 0; i < 4; ++i) \
        ab[i] = *(const short8*)((P) + ((MB)+i)*2048); }
#define LDBB(P) \
    { _Pragma("unroll") for (int n = 0; n < 4; ++n) \
        bb[n] = *(const short8*)((P) + n*2048); }
#define MFMA_BF(MB) \
    { _Pragma("unroll") for (int i = 0; i < 4; ++i) \
      _Pragma("unroll") for (int n = 0; n < 4; ++n) \
        accf[(MB)+i][n] = __builtin_amdgcn_mfma_f32_16x16x32_bf16(ab[i], bb[n], accf[(MB)+i][n], 0, 0, 0); }

__global__ __launch_bounds__(512, 2)
void gemm_mix(const char* __restrict__ Aq,  // qx   M x 4096 i8
              const char* __restrict__ Bq,  // qb   N x 4096 i8
              const char* __restrict__ Ab,  // acts M x 512B bf16
              const char* __restrict__ Bb,  // wob  N x 512B bf16
              const float* __restrict__ rscale,
              const float* __restrict__ cscale,
              const float* __restrict__ bias,
              float* __restrict__ out)
{
    __shared__ __attribute__((aligned(16))) char smem[131072];   // 128 KiB

    const int tid = threadIdx.x;
    const int wv = tid >> 6, lane = tid & 63;
    const int wm = wv >> 2, wn = wv & 3;
    const int wn1 = wn & 1, whb = wn >> 1;
    const int fr = lane & 15, kq4 = lane >> 4;
    const int rsw = (fr & 7) << 4;               // read-side XOR (bytes)

    // 2D XCD map: xcd = bid&7 owns an 8bm x 8bn square (bijective, 512 blocks)
    const int bid = blockIdx.x;
    const int xcd = bid & 7, loc = bid >> 3;
    const int bm = ((xcd & 3) * 8 + (loc & 7)) * 256;
    const int bn = ((xcd >> 2) * 8 + (loc >> 3)) * 256;

    const int srow = tid >> 3;                   // 0..63
    const int scb  = ((tid & 7) * 16) ^ ((srow & 7) << 4);   // pre-swizzled col

    // ---- per-lane LDS read bases: XOR folded once; imm offsets at use ----
    const int offk0 = (kq4 * 16) ^ rsw;
    const int offk1 = (64 + kq4 * 16) ^ rsw;
    const char* rA00 = smem + wm * 16384 + fr * 128 + offk0;   // c=0, k0
    const char* rA01 = rA00 - offk0 + offk1;                   // c=0, k1
    const char* rA10 = rA00 + 65536;                           // c=1, k0
    const char* rA11 = rA01 + 65536;                           // c=1, k1
    const char* rB00 = smem + 32768 + whb * 16384 + (wn1 * 64 + fr) * 128 + offk0;
    const char* rB01 = rB00 - offk0 + offk1;
    const char* rB10 = rB00 + 65536;
    const char* rB11 = rB01 + 65536;

    // ---- LDS stage destinations (wave-uniform, static) ----
    char* dA0 = smem + wv * 1024;                // buf0 A
    char* dA1 = dA0 + 65536;                     // buf1 A
    char* dB0 = smem + 32768 + wv * 1024;        // buf0 B
    char* dB1 = dB0 + 65536;                     // buf1 B

    // ---- persistent stage sources, advanced +128 per staged tile ----
    const char* sA0 = Aq + (size_t)(bm + srow) * IN_F + scb;         // h=0
    const char* sA1 = Aq + (size_t)(bm + 128 + srow) * IN_F + scb;   // h=1
    const char* sB0 = Bq + (size_t)(bn + srow) * IN_F + scb;
    const char* sB1 = Bq + (size_t)(bn + 128 + srow) * IN_F + scb;

    auto stg = [&](const char*& p, char* d, size_t rs) {
        stage16(p, d);
        stage16(p + 64 * rs, d + 8192);
        p += 128;
    };

    // =========================== Loop 1: int8 ===========================
    v4i acci[8][4] = {};
    {
        auto tile_i8 = [&](const char* rAk0, const char* rAk1,
                           const char* rBk0, const char* rBk1,
                           char* dstA, char* dstB, bool doA, bool doB) {
            v4i af[4], bf4[4];
            if (doA) { stg(sA0, dstA, IN_F); stg(sA1, dstA + 16384, IN_F); }
            LDB8(rBk0);
            LDA8(rAk0, 0);
            __builtin_amdgcn_s_setprio(1);
            MFMA_I8(0);
            __builtin_amdgcn_s_setprio(0);
            LDA8(rAk0, 4);
            __builtin_amdgcn_s_setprio(1);
            MFMA_I8(4);
            __builtin_amdgcn_s_setprio(0);
            LDB8(rBk1);
            LDA8(rAk1, 0);
            __builtin_amdgcn_s_setprio(1);
            MFMA_I8(0);
            __builtin_amdgcn_s_setprio(0);
            BARRIER();   // all waves consumed both B k-slices of this buf
            LDA8(rAk1, 4);
            if (doB) { stg(sB0, dstB, IN_F); stg(sB1, dstB + 16384, IN_F); }
            __builtin_amdgcn_s_setprio(1);
            MFMA_I8(4);
            __builtin_amdgcn_s_setprio(0);
            SB();
        };

        // prologue: B(0),A(0)->buf0, B(1)->buf1
        stg(sB0, dB0, IN_F); stg(sB1, dB0 + 16384, IN_F);
        stg(sA0, dA0, IN_F); stg(sA1, dA0 + 16384, IN_F);
        stg(sB0, dB1, IN_F); stg(sB1, dB1 + 16384, IN_F);
        SB();
        asm volatile("s_waitcnt vmcnt(4)" ::: "memory");
        BARRIER();

        for (int tp = 0; tp < NTI8 / 2; ++tp) {
            const int t = tp * 2;
            // even tile (c=0): stage A(t+1)->buf1, B(t+2)->buf0
            tile_i8(rA00, rA01, rB00, rB01, dA1, dB0, true, t + 2 < NTI8);
            if (t < NTI8 - 2)       asm volatile("s_waitcnt vmcnt(4)" ::: "memory");
            else                    asm volatile("s_waitcnt vmcnt(0)" ::: "memory");
            BARRIER();
            // odd tile (c=1): stage A(t+2)->buf0, B(t+3)->buf1
            tile_i8(rA10, rA11, rB10, rB11, dA0, dB1, t + 2 < NTI8, t + 3 < NTI8);
            if (t + 1 < NTI8 - 2)   asm volatile("s_waitcnt vmcnt(4)" ::: "memory");
            BARRIER();
        }
    }

    // exact i32 -> f32 convert, per fragment
    f32x4 accf[8][4];
    #pragma unroll
    for (int m = 0; m < 8; ++m)
        #pragma unroll
        for (int n = 0; n < 4; ++n) {
            const v4i q = acci[m][n];
            f32x4 f;
            #pragma unroll
            for (int r = 0; r < 4; ++r) f[r] = (float)q[r];
            accf[m][n] = f;
        }

    // ========================== Loop 2: bf16 tail ==========================
    {
        const char* sTA0 = Ab + (size_t)(bm + srow) * 512 + scb;
        const char* sTA1 = Ab + (size_t)(bm + 128 + srow) * 512 + scb;
        const char* sTB0 = Bb + (size_t)(bn + srow) * 512 + scb;
        const char* sTB1 = Bb + (size_t)(bn + 128 + srow) * 512 + scb;

        auto tile_bf = [&](const char* rAk0, const char* rAk1,
                           const char* rBk0, const char* rBk1,
                           char* dstA, char* dstB, bool doA, bool doB) {
            short8 ab[4], bb[4];
            if (doA) { stg(sTA0, dstA, 512); stg(sTA1, dstA + 16384, 512); }
            LDBB(rBk0);
            LDAB(rAk0, 0);
            __builtin_amdgcn_s_setprio(1);
            MFMA_BF(0);
            __builtin_amdgcn_s_setprio(0);
            LDAB(rAk0, 4);
            __builtin_amdgcn_s_setprio(1);
            MFMA_BF(4);
            __builtin_amdgcn_s_setprio(0);
            LDBB(rBk1);
            LDAB(rAk1, 0);
            __builtin_amdgcn_s_setprio(1);
            MFMA_BF(0);
            __builtin_amdgcn_s_setprio(0);
            BARRIER();
            LDAB(rAk1, 4);
            if (doB) { stg(sTB0, dstB, 512); stg(sTB1, dstB + 16384, 512); }
            __builtin_amdgcn_s_setprio(1);
            MFMA_BF(4);
            __builtin_amdgcn_s_setprio(0);
            SB();
        };

        stg(sTB0, dB0, 512); stg(sTB1, dB0 + 16384, 512);
        stg(sTA0, dA0, 512); stg(sTA1, dA0 + 16384, 512);
        stg(sTB0, dB1, 512); stg(sTB1, dB1 + 16384, 512);
        SB();
        asm volatile("s_waitcnt vmcnt(4)" ::: "memory");
        BARRIER();

        tile_bf(rA00, rA01, rB00, rB01, dA1, dB0, true,  true);   // t=0: A(1),B(2)
        asm volatile("s_waitcnt vmcnt(4)" ::: "memory");
        BARRIER();
        tile_bf(rA10, rA11, rB10, rB11, dA0, dB1, true,  true);   // t=1: A(2),B(3)  [FIX]
        asm volatile("s_waitcnt vmcnt(4)" ::: "memory");
        BARRIER();
        tile_bf(rA00, rA01, rB00, rB01, dA1, dB0, true,  false);  // t=2: A(3)
        asm volatile("s_waitcnt vmcnt(0)" ::: "memory");
        BARRIER();
        tile_bf(rA10, rA11, rB10, rB11, dA0, dB1, false, false);  // t=3
    }

    // epilogue: 16x16 C/D layout col = lane&15, row = (lane>>4)*4 + reg [m89]
    #pragma unroll
    for (int m = 0; m < 8; ++m) {
        const int rbase = bm + wm * 128 + m * 16 + kq4 * 4;
        #pragma unroll
        for (int n = 0; n < 4; ++n) {
            const int col = bn + wn * 64 + n * 16 + fr;
            const float csv = cscale[col];
            const float badd = bias[col];
            #pragma unroll
            for (int r = 0; r < 4; ++r) {
                const int row = rbase + r;
                out[(size_t)row * OUT_F + col] =
                    accf[m][n][r] * rscale[row] * csv + badd;
            }
        }
    }
}

// ---------------------------------------------------------------------------
extern "C" void kernel_launch(void* const* d_in, const int* in_sizes, int n_in,
                              void* d_out, int out_size, void* d_ws, size_t ws_size,
                              hipStream_t stream)
{
    const float* x         = (const float*)d_in[0];
    const int*   q_weight  = (const int*)d_in[1];    // int32 on device
    const float* scale_col = (const float*)d_in[2];
    const float* bias      = (const float*)d_in[3];
    const int*   ind       = (const int*)d_in[4];
    float*       out       = (float*)d_out;

    // workspace (~54 MB)
    char*           qx   = (char*)d_ws;                              // M x IN_F i8
    char*           qb   = qx + (size_t)M_DIM * IN_F;                // OUT_F x IN_F i8
    __hip_bfloat16* acts = (__hip_bfloat16*)(qb + (size_t)OUT_F * IN_F);  // M x NFP
    __hip_bfloat16* wob  = acts + (size_t)M_DIM * NFP;               // OUT_F x NFP
    float*          xs   = (float*)(wob + (size_t)OUT_F * NFP);      // M

    const size_t need = (size_t)((char*)(xs + M_DIM) - (char*)d_ws);
    if (ws_size < need) return;

    quant_rows<<<dim3(M_DIM / 4), dim3(256), 0, stream>>>(x, ind, qx, acts, xs);
    conv_w<<<dim3(OUT_F), dim3(256), 0, stream>>>(q_weight, ind, qb, wob);

    gemm_mix<<<dim3((M_DIM / 256) * (OUT_F / 256)), dim3(512), 0, stream>>>(
        qx, qb, (const char*)acts, (const char*)wob,
        xs, scale_col, bias, out);
}

// Round 17
// 198.837 us; speedup vs baseline: 1.0176x; 1.0024x over previous
//
#include <hip/hip_runtime.h>
#include <hip/hip_bf16.h>
#include <stdint.h>

#define M_DIM 8192
#define IN_F  4096
#define OUT_F 4096
#define NFP   256
#define NTI8  32              // i8 byte-tiles (4096 B / 128 B)
#define NTB   4               // bf16 tail byte-tiles (512 B / 128 B)

typedef __attribute__((ext_vector_type(4)))  int   v4i;
typedef __attribute__((ext_vector_type(8)))  short short8;
typedef __attribute__((ext_vector_type(4)))  float f32x4;

__device__ __forceinline__ void stage16(const void* g, void* l) {
    __builtin_amdgcn_global_load_lds(
        (const __attribute__((address_space(1))) int*)g,
        (__attribute__((address_space(3))) int*)l,
        16, 0, 0);
}

#define SB() __builtin_amdgcn_sched_barrier(0)
#define BARRIER() do { SB(); __builtin_amdgcn_s_barrier(); SB(); } while (0)

// ---------------------------------------------------------------------------
// Kernel 1: per-row quantization, 4 rows per block (verified R12-R14).
// ---------------------------------------------------------------------------
__global__ __launch_bounds__(256)
void quant_rows(const float* __restrict__ x,
                const int* __restrict__ ind,
                char* __restrict__ qx,
                __hip_bfloat16* __restrict__ acts,
                float* __restrict__ xscale)
{
    __shared__ short omap[IN_F];
    __shared__ float red[4];
    __shared__ float s_xs;

    const int t = threadIdx.x;

    #pragma unroll
    for (int i = 0; i < IN_F / 256; ++i) omap[t + i * 256] = -1;
    __syncthreads();
    omap[ind[t]] = (short)t;
    __syncthreads();

    short om[16];
    #pragma unroll
    for (int j = 0; j < 16; ++j) om[j] = omap[t * 16 + j];

    for (int r = 0; r < 4; ++r) {
        const int row = blockIdx.x * 4 + r;

        const float* xr = x + (size_t)row * IN_F + t * 16;
        float v[16];
        #pragma unroll
        for (int j = 0; j < 4; ++j) {
            float4 f = *(const float4*)(xr + j * 4);
            v[j*4+0] = f.x; v[j*4+1] = f.y; v[j*4+2] = f.z; v[j*4+3] = f.w;
        }

        float m_nz = 0.f;
        #pragma unroll
        for (int j = 0; j < 16; ++j) {
            float a = fabsf(v[j]);
            if (om[j] < 0) m_nz = fmaxf(m_nz, a);
        }
        #pragma unroll
        for (int off = 32; off > 0; off >>= 1)
            m_nz = fmaxf(m_nz, __shfl_down(m_nz, off));
        if ((t & 63) == 0) red[t >> 6] = m_nz;
        __syncthreads();
        if (t == 0) {
            float a = fmaxf(fmaxf(red[0], red[1]), fmaxf(red[2], red[3]));
            xscale[row] = a / 127.0f;
            s_xs = (a > 0.f) ? (a / 127.0f) : 1.0f;
        }
        __syncthreads();
        const float xs = s_xs;

        union { char c[16]; int4 q; } u;
        #pragma unroll
        for (int j = 0; j < 16; ++j) {
            if (om[j] >= 0) {
                acts[(size_t)row * NFP + om[j]] = __float2bfloat16(v[j] / xs);
                u.c[j] = 0;
            } else {
                float rr = rintf(v[j] / xs);          // half-to-even == jnp.round
                rr = fminf(fmaxf(rr, -128.f), 127.f);
                u.c[j] = (char)(int)rr;
            }
        }
        *(int4*)(qx + (size_t)row * IN_F + t * 16) = u.q;
    }
}

// ---------------------------------------------------------------------------
// Kernel 2: weight int32 -> int8 (exact) + outlier gather (verified).
// ---------------------------------------------------------------------------
__global__ __launch_bounds__(256)
void conv_w(const int* __restrict__ qw, const int* __restrict__ ind,
            char* __restrict__ qb, __hip_bfloat16* __restrict__ wob)
{
    const int n = blockIdx.x;
    const int t = threadIdx.x;
    const int* src = qw + (size_t)n * IN_F + t * 16;
    union { char c[16]; int4 q; } u;
    #pragma unroll
    for (int j = 0; j < 4; ++j) {
        int4 raw = *(const int4*)(src + j * 4);
        u.c[j*4+0] = (char)raw.x; u.c[j*4+1] = (char)raw.y;
        u.c[j*4+2] = (char)raw.z; u.c[j*4+3] = (char)raw.w;
    }
    *(int4*)(qb + (size_t)n * IN_F + t * 16) = u.q;
    wob[(size_t)n * NFP + t] = __float2bfloat16((float)qw[(size_t)n * IN_F + ind[t]]);
}

// ---------------------------------------------------------------------------
// Kernel 3: R13 schedule + induction-variable addressing (R15), with the
// R15 bug fixed: bf16 tail tile t=1 MUST stage B(3)->buf1 (R13 staged
// B(t+2) for t<2; the unrolled call had doB=false -> tile 3 read stale B(1)).
// ---------------------------------------------------------------------------
#define LDA8(P, MB) \
    { _Pragma("unroll") for (int i = 0; i < 4; ++i) \
        af[i] = *(const v4i*)((P) + ((MB)+i)*2048); }
#define LDB8(P) \
    { _Pragma("unroll") for (int n = 0; n < 4; ++n) \
        bf4[n] = *(const v4i*)((P) + n*2048); }
#define MFMA_I8(MB) \
    { _Pragma("unroll") for (int i = 0; i < 4; ++i) \
      _Pragma("unroll") for (int n = 0; n < 4; ++n) \
        acci[(MB)+i][n] = __builtin_amdgcn_mfma_i32_16x16x64_i8(af[i], bf4[n], acci[(MB)+i][n], 0, 0, 0); }

#define LDAB(P, MB) \
    { _Pragma("unroll") for (int i = 0; i < 4; ++i) \
        ab[i] = *(const short8*)((P) + ((MB)+i)*2048); }
#define LDBB(P) \
    { _Pragma("unroll") for (int n = 0; n < 4; ++n) \
        bb[n] = *(const short8*)((P) + n*2048); }
#define MFMA_BF(MB) \
    { _Pragma("unroll") for (int i = 0; i < 4; ++i) \
      _Pragma("unroll") for (int n = 0; n < 4; ++n) \
        accf[(MB)+i][n] = __builtin_amdgcn_mfma_f32_16x16x32_bf16(ab[i], bb[n], accf[(MB)+i][n], 0, 0, 0); }

__global__ __launch_bounds__(512, 2)
void gemm_mix(const char* __restrict__ Aq,  // qx   M x 4096 i8
              const char* __restrict__ Bq,  // qb   N x 4096 i8
              const char* __restrict__ Ab,  // acts M x 512B bf16
              const char* __restrict__ Bb,  // wob  N x 512B bf16
              const float* __restrict__ rscale,
              const float* __restrict__ cscale,
              const float* __restrict__ bias,
              float* __restrict__ out)
{
    __shared__ __attribute__((aligned(16))) char smem[131072];   // 128 KiB

    const int tid = threadIdx.x;
    const int wv = tid >> 6, lane = tid & 63;
    const int wm = wv >> 2, wn = wv & 3;
    const int wn1 = wn & 1, whb = wn >> 1;
    const int fr = lane & 15, kq4 = lane >> 4;
    const int rsw = (fr & 7) << 4;               // read-side XOR (bytes)

    // 2D XCD map: xcd = bid&7 owns an 8bm x 8bn square (bijective, 512 blocks)
    const int bid = blockIdx.x;
    const int xcd = bid & 7, loc = bid >> 3;
    const int bm = ((xcd & 3) * 8 + (loc & 7)) * 256;
    const int bn = ((xcd >> 2) * 8 + (loc >> 3)) * 256;

    const int srow = tid >> 3;                   // 0..63
    const int scb  = ((tid & 7) * 16) ^ ((srow & 7) << 4);   // pre-swizzled col

    // ---- per-lane LDS read bases: XOR folded once; imm offsets at use ----
    const int offk0 = (kq4 * 16) ^ rsw;
    const int offk1 = (64 + kq4 * 16) ^ rsw;
    const char* rA00 = smem + wm * 16384 + fr * 128 + offk0;   // c=0, k0
    const char* rA01 = rA00 - offk0 + offk1;                   // c=0, k1
    const char* rA10 = rA00 + 65536;                           // c=1, k0
    const char* rA11 = rA01 + 65536;                           // c=1, k1
    const char* rB00 = smem + 32768 + whb * 16384 + (wn1 * 64 + fr) * 128 + offk0;
    const char* rB01 = rB00 - offk0 + offk1;
    const char* rB10 = rB00 + 65536;
    const char* rB11 = rB01 + 65536;

    // ---- LDS stage destinations (wave-uniform, static) ----
    char* dA0 = smem + wv * 1024;                // buf0 A
    char* dA1 = dA0 + 65536;                     // buf1 A
    char* dB0 = smem + 32768 + wv * 1024;        // buf0 B
    char* dB1 = dB0 + 65536;                     // buf1 B

    // ---- persistent stage sources, advanced +128 per staged tile ----
    const char* sA0 = Aq + (size_t)(bm + srow) * IN_F + scb;         // h=0
    const char* sA1 = Aq + (size_t)(bm + 128 + srow) * IN_F + scb;   // h=1
    const char* sB0 = Bq + (size_t)(bn + srow) * IN_F + scb;
    const char* sB1 = Bq + (size_t)(bn + 128 + srow) * IN_F + scb;

    auto stg = [&](const char*& p, char* d, size_t rs) {
        stage16(p, d);
        stage16(p + 64 * rs, d + 8192);
        p += 128;
    };

    // =========================== Loop 1: int8 ===========================
    v4i acci[8][4] = {};
    {
        auto tile_i8 = [&](const char* rAk0, const char* rAk1,
                           const char* rBk0, const char* rBk1,
                           char* dstA, char* dstB, bool doA, bool doB) {
            v4i af[4], bf4[4];
            if (doA) { stg(sA0, dstA, IN_F); stg(sA1, dstA + 16384, IN_F); }
            LDB8(rBk0);
            LDA8(rAk0, 0);
            __builtin_amdgcn_s_setprio(1);
            MFMA_I8(0);
            __builtin_amdgcn_s_setprio(0);
            LDA8(rAk0, 4);
            __builtin_amdgcn_s_setprio(1);
            MFMA_I8(4);
            __builtin_amdgcn_s_setprio(0);
            LDB8(rBk1);
            LDA8(rAk1, 0);
            __builtin_amdgcn_s_setprio(1);
            MFMA_I8(0);
            __builtin_amdgcn_s_setprio(0);
            BARRIER();   // all waves consumed both B k-slices of this buf
            LDA8(rAk1, 4);
            if (doB) { stg(sB0, dstB, IN_F); stg(sB1, dstB + 16384, IN_F); }
            __builtin_amdgcn_s_setprio(1);
            MFMA_I8(4);
            __builtin_amdgcn_s_setprio(0);
            SB();
        };

        // prologue: B(0),A(0)->buf0, B(1)->buf1
        stg(sB0, dB0, IN_F); stg(sB1, dB0 + 16384, IN_F);
        stg(sA0, dA0, IN_F); stg(sA1, dA0 + 16384, IN_F);
        stg(sB0, dB1, IN_F); stg(sB1, dB1 + 16384, IN_F);
        SB();
        asm volatile("s_waitcnt vmcnt(4)" ::: "memory");
        BARRIER();

        for (int tp = 0; tp < NTI8 / 2; ++tp) {
            const int t = tp * 2;
            // even tile (c=0): stage A(t+1)->buf1, B(t+2)->buf0
            tile_i8(rA00, rA01, rB00, rB01, dA1, dB0, true, t + 2 < NTI8);
            if (t < NTI8 - 2)       asm volatile("s_waitcnt vmcnt(4)" ::: "memory");
            else                    asm volatile("s_waitcnt vmcnt(0)" ::: "memory");
            BARRIER();
            // odd tile (c=1): stage A(t+2)->buf0, B(t+3)->buf1
            tile_i8(rA10, rA11, rB10, rB11, dA0, dB1, t + 2 < NTI8, t + 3 < NTI8);
            if (t + 1 < NTI8 - 2)   asm volatile("s_waitcnt vmcnt(4)" ::: "memory");
            BARRIER();
        }
    }

    // exact i32 -> f32 convert, per fragment
    f32x4 accf[8][4];
    #pragma unroll
    for (int m = 0; m < 8; ++m)
        #pragma unroll
        for (int n = 0; n < 4; ++n) {
            const v4i q = acci[m][n];
            f32x4 f;
            #pragma unroll
            for (int r = 0; r < 4; ++r) f[r] = (float)q[r];
            accf[m][n] = f;
        }

    // ========================== Loop 2: bf16 tail ==========================
    {
        const char* sTA0 = Ab + (size_t)(bm + srow) * 512 + scb;
        const char* sTA1 = Ab + (size_t)(bm + 128 + srow) * 512 + scb;
        const char* sTB0 = Bb + (size_t)(bn + srow) * 512 + scb;
        const char* sTB1 = Bb + (size_t)(bn + 128 + srow) * 512 + scb;

        auto tile_bf = [&](const char* rAk0, const char* rAk1,
                           const char* rBk0, const char* rBk1,
                           char* dstA, char* dstB, bool doA, bool doB) {
            short8 ab[4], bb[4];
            if (doA) { stg(sTA0, dstA, 512); stg(sTA1, dstA + 16384, 512); }
            LDBB(rBk0);
            LDAB(rAk0, 0);
            __builtin_amdgcn_s_setprio(1);
            MFMA_BF(0);
            __builtin_amdgcn_s_setprio(0);
            LDAB(rAk0, 4);
            __builtin_amdgcn_s_setprio(1);
            MFMA_BF(4);
            __builtin_amdgcn_s_setprio(0);
            LDBB(rBk1);
            LDAB(rAk1, 0);
            __builtin_amdgcn_s_setprio(1);
            MFMA_BF(0);
            __builtin_amdgcn_s_setprio(0);
            BARRIER();
            LDAB(rAk1, 4);
            if (doB) { stg(sTB0, dstB, 512); stg(sTB1, dstB + 16384, 512); }
            __builtin_amdgcn_s_setprio(1);
            MFMA_BF(4);
            __builtin_amdgcn_s_setprio(0);
            SB();
        };

        stg(sTB0, dB0, 512); stg(sTB1, dB0 + 16384, 512);
        stg(sTA0, dA0, 512); stg(sTA1, dA0 + 16384, 512);
        stg(sTB0, dB1, 512); stg(sTB1, dB1 + 16384, 512);
        SB();
        asm volatile("s_waitcnt vmcnt(4)" ::: "memory");
        BARRIER();

        tile_bf(rA00, rA01, rB00, rB01, dA1, dB0, true,  true);   // t=0: A(1),B(2)
        asm volatile("s_waitcnt vmcnt(4)" ::: "memory");
        BARRIER();
        tile_bf(rA10, rA11, rB10, rB11, dA0, dB1, true,  true);   // t=1: A(2),B(3)  [FIX]
        asm volatile("s_waitcnt vmcnt(4)" ::: "memory");
        BARRIER();
        tile_bf(rA00, rA01, rB00, rB01, dA1, dB0, true,  false);  // t=2: A(3)
        asm volatile("s_waitcnt vmcnt(0)" ::: "memory");
        BARRIER();
        tile_bf(rA10, rA11, rB10, rB11, dA0, dB1, false, false);  // t=3
    }

    // epilogue: 16x16 C/D layout col = lane&15, row = (lane>>4)*4 + reg [m89]
    #pragma unroll
    for (int m = 0; m < 8; ++m) {
        const int rbase = bm + wm * 128 + m * 16 + kq4 * 4;
        #pragma unroll
        for (int n = 0; n < 4; ++n) {
            const int col = bn + wn * 64 + n * 16 + fr;
            const float csv = cscale[col];
            const float badd = bias[col];
            #pragma unroll
            for (int r = 0; r < 4; ++r) {
                const int row = rbase + r;
                out[(size_t)row * OUT_F + col] =
                    accf[m][n][r] * rscale[row] * csv + badd;
            }
        }
    }
}

// ---------------------------------------------------------------------------
extern "C" void kernel_launch(void* const* d_in, const int* in_sizes, int n_in,
                              void* d_out, int out_size, void* d_ws, size_t ws_size,
                              hipStream_t stream)
{
    const float* x         = (const float*)d_in[0];
    const int*   q_weight  = (const int*)d_in[1];    // int32 on device
    const float* scale_col = (const float*)d_in[2];
    const float* bias      = (const float*)d_in[3];
    const int*   ind       = (const int*)d_in[4];
    float*       out       = (float*)d_out;

    // workspace (~54 MB)
    char*           qx   = (char*)d_ws;                              // M x IN_F i8
    char*           qb   = qx + (size_t)M_DIM * IN_F;                // OUT_F x IN_F i8
    __hip_bfloat16* acts = (__hip_bfloat16*)(qb + (size_t)OUT_F * IN_F);  // M x NFP
    __hip_bfloat16* wob  = acts + (size_t)M_DIM * NFP;               // OUT_F x NFP
    float*          xs   = (float*)(wob + (size_t)OUT_F * NFP);      // M

    const size_t need = (size_t)((char*)(xs + M_DIM) - (char*)d_ws);
    if (ws_size < need) return;

    quant_rows<<<dim3(M_DIM / 4), dim3(256), 0, stream>>>(x, ind, qx, acts, xs);
    conv_w<<<dim3(OUT_F), dim3(256), 0, stream>>>(q_weight, ind, qb, wob);

    gemm_mix<<<dim3((M_DIM / 256) * (OUT_F / 256)), dim3(512), 0, stream>>>(
        qx, qb, (const char*)acts, (const char*)wob,
        xs, scale_col, bias, out);
}